// Round 1
// 342.419 us; speedup vs baseline: 1.0987x; 1.0987x over previous
//
#include <hip/hip_runtime.h>

typedef __bf16 bf16x8 __attribute__((ext_vector_type(8)));
typedef unsigned short u16x8v __attribute__((ext_vector_type(8)));
typedef unsigned short u16x4v __attribute__((ext_vector_type(4)));
typedef float f32x4 __attribute__((ext_vector_type(4)));

constexpr int SEQ = 2048;
constexpr int DIM = 1024;
constexpr int BATCH = 4;
constexpr size_t NBS = (size_t)BATCH * SEQ * DIM;  // 8388608

static __device__ __forceinline__ unsigned short f2bf(float f) {
    unsigned int u = __builtin_bit_cast(unsigned int, f);
    u += 0x7FFFu + ((u >> 16) & 1u);  // RNE
    return (unsigned short)(u >> 16);
}
static __device__ __forceinline__ float bf2f(unsigned short h) {
    return __builtin_bit_cast(float, (unsigned int)h << 16);
}
static __device__ __forceinline__ bf16x8 ldsld(const unsigned short* p) {
    return __builtin_bit_cast(bf16x8, *(const u16x8v*)p);
}
// Async global->LDS, 16B/lane. LDS dest = wave-uniform base + lane*16B.
static __device__ __forceinline__ void gld_lds16(const unsigned short* g, unsigned short* l) {
    __builtin_amdgcn_global_load_lds(
        (const __attribute__((address_space(1))) void*)g,
        (__attribute__((address_space(3))) void*)l, 16, 0, 0);
}

// ---------------------------------------------------------------------------
// fp32 -> bf16 hi + bf16 lo (lo = rne(x - hi)); 4 elems/thread.
// ---------------------------------------------------------------------------
__global__ __launch_bounds__(256) void split_f32(
    const float* __restrict__ in, unsigned short* __restrict__ hi,
    unsigned short* __restrict__ lo, int n4)
{
    int i = blockIdx.x * 256 + threadIdx.x;
    if (i >= n4) return;
    float4 f = ((const float4*)in)[i];
    u16x4v h, l;
    h.x = f2bf(f.x); l.x = f2bf(f.x - bf2f(h.x));
    h.y = f2bf(f.y); l.y = f2bf(f.y - bf2f(h.y));
    h.z = f2bf(f.z); l.z = f2bf(f.z - bf2f(h.z));
    h.w = f2bf(f.w); l.w = f2bf(f.w - bf2f(h.w));
    ((u16x4v*)hi)[i] = h;
    ((u16x4v*)lo)[i] = l;
}

// ---------------------------------------------------------------------------
// Q/K projection, split-3 MFMA (hh+hl+lh), NT, W [out,in]. 128x128 tile,
// 4 waves x 64x64 (4x4 MFMA 16x16x32). z=0 -> Qh, z=1 -> Kh (bf16 hi only).
// Staging via global_load_lds width=16 (m97 recipe): linear [128][32] tiles,
// wave w stages rows [w*32, w*32+32) with two calls of 16 rows each.
// ---------------------------------------------------------------------------
__global__ __launch_bounds__(256) void qk_gemm3(
    const unsigned short* __restrict__ Xh, const unsigned short* __restrict__ Xl,
    const unsigned short* __restrict__ Wh, const unsigned short* __restrict__ Wl,
    unsigned short* __restrict__ Qh, unsigned short* __restrict__ Kh)
{
    __shared__ __attribute__((aligned(16))) unsigned short Ah[128 * 32], Al[128 * 32];
    __shared__ __attribute__((aligned(16))) unsigned short Bh[128 * 32], Bl[128 * 32];
    const int m0 = blockIdx.x * 128, n0 = blockIdx.y * 128, z = blockIdx.z;
    const unsigned short* Wzh = Wh + (size_t)z * DIM * DIM;
    const unsigned short* Wzl = Wl + (size_t)z * DIM * DIM;
    const int tid = threadIdx.x;
    const int w = tid >> 6, lane = tid & 63, q = lane >> 4, c = lane & 15;
    const int wrow = (w >> 1) * 64, wcol = (w & 1) * 64;
    const int grow = w * 32 + (lane >> 2);   // staging row (first call)
    const int gcol = (lane & 3) * 8;         // staging col offset (shorts)
    unsigned short* lA  = Ah + w * 1024;     // wave-uniform LDS bases
    unsigned short* lAl = Al + w * 1024;
    unsigned short* lB  = Bh + w * 1024;
    unsigned short* lBl = Bl + w * 1024;

    f32x4 acc[4][4];
#pragma unroll
    for (int a = 0; a < 4; ++a)
#pragma unroll
        for (int b = 0; b < 4; ++b) acc[a][b] = (f32x4){0.f, 0.f, 0.f, 0.f};

    for (int k0 = 0; k0 < DIM; k0 += 32) {
        __syncthreads();
        {
            const size_t ga = (size_t)(m0 + grow) * DIM + k0 + gcol;
            const size_t gb = (size_t)(n0 + grow) * DIM + k0 + gcol;
            gld_lds16(Xh + ga, lA);
            gld_lds16(Xh + ga + (size_t)16 * DIM, lA + 512);
            gld_lds16(Xl + ga, lAl);
            gld_lds16(Xl + ga + (size_t)16 * DIM, lAl + 512);
            gld_lds16(Wzh + gb, lB);
            gld_lds16(Wzh + gb + (size_t)16 * DIM, lB + 512);
            gld_lds16(Wzl + gb, lBl);
            gld_lds16(Wzl + gb + (size_t)16 * DIM, lBl + 512);
        }
        __syncthreads();
        bf16x8 ah[4], al[4], bh[4], bl[4];
#pragma unroll
        for (int mi = 0; mi < 4; ++mi) {
            ah[mi] = ldsld(Ah + (wrow + mi * 16 + c) * 32 + q * 8);
            al[mi] = ldsld(Al + (wrow + mi * 16 + c) * 32 + q * 8);
        }
#pragma unroll
        for (int ni = 0; ni < 4; ++ni) {
            bh[ni] = ldsld(Bh + (wcol + ni * 16 + c) * 32 + q * 8);
            bl[ni] = ldsld(Bl + (wcol + ni * 16 + c) * 32 + q * 8);
        }
#pragma unroll
        for (int mi = 0; mi < 4; ++mi)
#pragma unroll
            for (int ni = 0; ni < 4; ++ni) {
                acc[mi][ni] = __builtin_amdgcn_mfma_f32_16x16x32_bf16(al[mi], bh[ni], acc[mi][ni], 0, 0, 0);
                acc[mi][ni] = __builtin_amdgcn_mfma_f32_16x16x32_bf16(ah[mi], bl[ni], acc[mi][ni], 0, 0, 0);
                acc[mi][ni] = __builtin_amdgcn_mfma_f32_16x16x32_bf16(ah[mi], bh[ni], acc[mi][ni], 0, 0, 0);
            }
    }

    unsigned short* OH = z ? Kh : Qh;
#pragma unroll
    for (int mi = 0; mi < 4; ++mi)
#pragma unroll
        for (int ni = 0; ni < 4; ++ni) {
            const int col = n0 + wcol + ni * 16 + c;
#pragma unroll
            for (int r = 0; r < 4; ++r) {
                const int row = m0 + wrow + mi * 16 + q * 4 + r;
                OH[(size_t)row * DIM + col] = f2bf(acc[mi][ni][r]);
            }
        }
}

// ---------------------------------------------------------------------------
// V projection, single hh MFMA term. Output stored transposed Vt[b][d][s].
// ---------------------------------------------------------------------------
__global__ __launch_bounds__(256) void v_gemm1(
    const unsigned short* __restrict__ Xh, const unsigned short* __restrict__ Wh,
    unsigned short* __restrict__ Vt)
{
    __shared__ __attribute__((aligned(16))) unsigned short Ah[128 * 32];
    __shared__ __attribute__((aligned(16))) unsigned short Bh[128 * 32];
    const int m0 = blockIdx.x * 128, n0 = blockIdx.y * 128;
    const int tid = threadIdx.x;
    const int w = tid >> 6, lane = tid & 63, q = lane >> 4, c = lane & 15;
    const int wrow = (w >> 1) * 64, wcol = (w & 1) * 64;
    const int grow = w * 32 + (lane >> 2);
    const int gcol = (lane & 3) * 8;
    unsigned short* lA = Ah + w * 1024;
    unsigned short* lB = Bh + w * 1024;

    f32x4 acc[4][4];
#pragma unroll
    for (int a = 0; a < 4; ++a)
#pragma unroll
        for (int b = 0; b < 4; ++b) acc[a][b] = (f32x4){0.f, 0.f, 0.f, 0.f};

    for (int k0 = 0; k0 < DIM; k0 += 32) {
        __syncthreads();
        {
            const size_t ga = (size_t)(m0 + grow) * DIM + k0 + gcol;
            const size_t gb = (size_t)(n0 + grow) * DIM + k0 + gcol;
            gld_lds16(Xh + ga, lA);
            gld_lds16(Xh + ga + (size_t)16 * DIM, lA + 512);
            gld_lds16(Wh + gb, lB);
            gld_lds16(Wh + gb + (size_t)16 * DIM, lB + 512);
        }
        __syncthreads();
        bf16x8 ah[4], bh[4];
#pragma unroll
        for (int mi = 0; mi < 4; ++mi)
            ah[mi] = ldsld(Ah + (wrow + mi * 16 + c) * 32 + q * 8);
#pragma unroll
        for (int ni = 0; ni < 4; ++ni)
            bh[ni] = ldsld(Bh + (wcol + ni * 16 + c) * 32 + q * 8);
#pragma unroll
        for (int mi = 0; mi < 4; ++mi)
#pragma unroll
            for (int ni = 0; ni < 4; ++ni)
                acc[mi][ni] = __builtin_amdgcn_mfma_f32_16x16x32_bf16(ah[mi], bh[ni], acc[mi][ni], 0, 0, 0);
    }
#pragma unroll
    for (int mi = 0; mi < 4; ++mi) {
        const int mg = m0 + wrow + mi * 16 + q * 4;
        const int bb = mg >> 11, ss = mg & (SEQ - 1);
#pragma unroll
        for (int ni = 0; ni < 4; ++ni) {
            const int col = n0 + wcol + ni * 16 + c;
            u16x4v v;
            v.x = f2bf(acc[mi][ni][0]);
            v.y = f2bf(acc[mi][ni][1]);
            v.z = f2bf(acc[mi][ni][2]);
            v.w = f2bf(acc[mi][ni][3]);
            *(u16x4v*)(Vt + ((size_t)bb * DIM + col) * SEQ + ss) = v;
        }
    }
}

// ---------------------------------------------------------------------------
// Scores GEMM, ALL batches in one launch: S = Qh Kh^T * SCALE, bf16 out.
// Grid (16,16,BATCH); skips tiles entirely above the diagonal.
// ---------------------------------------------------------------------------
__global__ __launch_bounds__(256) void scores_gemm1b(
    const unsigned short* __restrict__ Q, const unsigned short* __restrict__ K,
    unsigned short* __restrict__ S)
{
    if (blockIdx.y > blockIdx.x) return;
    __shared__ __attribute__((aligned(16))) unsigned short Ah[128 * 32];
    __shared__ __attribute__((aligned(16))) unsigned short Bh[128 * 32];
    const int i0 = blockIdx.x * 128, j0 = blockIdx.y * 128, b = blockIdx.z;
    const unsigned short* Qb = Q + (size_t)b * SEQ * DIM;
    const unsigned short* Kb = K + (size_t)b * SEQ * DIM;
    unsigned short* Sb = S + (size_t)b * SEQ * SEQ;
    const int tid = threadIdx.x;
    const int w = tid >> 6, lane = tid & 63, q = lane >> 4, c = lane & 15;
    const int wrow = (w >> 1) * 64, wcol = (w & 1) * 64;
    const int grow = w * 32 + (lane >> 2);
    const int gcol = (lane & 3) * 8;
    unsigned short* lA = Ah + w * 1024;
    unsigned short* lB = Bh + w * 1024;

    f32x4 acc[4][4];
#pragma unroll
    for (int a = 0; a < 4; ++a)
#pragma unroll
        for (int bq = 0; bq < 4; ++bq) acc[a][bq] = (f32x4){0.f, 0.f, 0.f, 0.f};

    for (int k0 = 0; k0 < DIM; k0 += 32) {
        __syncthreads();
        {
            const size_t ga = (size_t)(i0 + grow) * DIM + k0 + gcol;
            const size_t gb = (size_t)(j0 + grow) * DIM + k0 + gcol;
            gld_lds16(Qb + ga, lA);
            gld_lds16(Qb + ga + (size_t)16 * DIM, lA + 512);
            gld_lds16(Kb + gb, lB);
            gld_lds16(Kb + gb + (size_t)16 * DIM, lB + 512);
        }
        __syncthreads();
        bf16x8 ah[4], bh[4];
#pragma unroll
        for (int mi = 0; mi < 4; ++mi)
            ah[mi] = ldsld(Ah + (wrow + mi * 16 + c) * 32 + q * 8);
#pragma unroll
        for (int ni = 0; ni < 4; ++ni)
            bh[ni] = ldsld(Bh + (wcol + ni * 16 + c) * 32 + q * 8);
#pragma unroll
        for (int mi = 0; mi < 4; ++mi)
#pragma unroll
            for (int ni = 0; ni < 4; ++ni)
                acc[mi][ni] = __builtin_amdgcn_mfma_f32_16x16x32_bf16(ah[mi], bh[ni], acc[mi][ni], 0, 0, 0);
    }
#pragma unroll
    for (int mi = 0; mi < 4; ++mi)
#pragma unroll
        for (int ni = 0; ni < 4; ++ni) {
            const int col = j0 + wcol + ni * 16 + c;
#pragma unroll
            for (int r = 0; r < 4; ++r) {
                const int row = i0 + wrow + mi * 16 + q * 4 + r;
                Sb[(size_t)row * SEQ + col] = f2bf(acc[mi][ni][r] * 0.03125f);
            }
        }
}

// ---------------------------------------------------------------------------
// Row-wise masked softmax, ALL batches: bf16 S -> bf16 P (full rows).
// Faithful: j > i masked; j <= i masked iff S == 0. Grid (SEQ, BATCH).
// Vectorized: thread t owns the contiguous 8-element chunk [8t, 8t+8).
// ---------------------------------------------------------------------------
__global__ __launch_bounds__(256) void softmax_row_b(
    const unsigned short* __restrict__ S, unsigned short* __restrict__ P)
{
    const int i = blockIdx.x, t = threadIdx.x;
    const size_t ro = ((size_t)blockIdx.y * SEQ + i) * SEQ;
    const int wid = t >> 6, lane = t & 63;
    __shared__ float redm[4], reds[4];
    const int j0 = t * 8;
    u16x8v raw = *(const u16x8v*)(S + ro + j0);
    float sv[8];
    float mx = -__builtin_inff();
#pragma unroll
    for (int u = 0; u < 8; ++u) {
        float s = -__builtin_inff();
        if (j0 + u <= i) {
            float x = bf2f(raw[u]);
            s = (x == 0.f) ? -__builtin_inff() : x;
        }
        sv[u] = s;
        mx = fmaxf(mx, s);
    }
#pragma unroll
    for (int off = 1; off < 64; off <<= 1) mx = fmaxf(mx, __shfl_xor(mx, off));
    if (lane == 0) redm[wid] = mx;
    __syncthreads();
    const float M = fmaxf(fmaxf(redm[0], redm[1]), fmaxf(redm[2], redm[3]));
    float sum = 0.f;
#pragma unroll
    for (int u = 0; u < 8; ++u) {
        float e = __expf(sv[u] - M);
        sv[u] = e;
        sum += e;
    }
#pragma unroll
    for (int off = 1; off < 64; off <<= 1) sum += __shfl_xor(sum, off);
    if (lane == 0) reds[wid] = sum;
    __syncthreads();
    const float rinv = 1.f / (reds[0] + reds[1] + reds[2] + reds[3]);
    u16x8v o;
#pragma unroll
    for (int u = 0; u < 8; ++u) o[u] = f2bf(sv[u] * rinv);
    *(u16x8v*)(P + ro + j0) = o;
}

// ---------------------------------------------------------------------------
// out = P @ V via Vt (NT MFMA), fp32 store. 128x128 tile (4x4 acc);
// k-loop truncated at causal bound i0+128.
// ---------------------------------------------------------------------------
__global__ __launch_bounds__(256) void pv_gemm(
    const unsigned short* __restrict__ Pm, const unsigned short* __restrict__ Vt,
    float* __restrict__ Out)
{
    __shared__ __attribute__((aligned(16))) unsigned short Ps[128 * 32];
    __shared__ __attribute__((aligned(16))) unsigned short Vs[128 * 32];
    const int i0 = blockIdx.x * 128, d0 = blockIdx.y * 128, b = blockIdx.z;
    const int tid = threadIdx.x;
    const int w = tid >> 6, lane = tid & 63, q = lane >> 4, c = lane & 15;
    const int wrow = (w >> 1) * 64, wcol = (w & 1) * 64;
    const int grow = w * 32 + (lane >> 2);
    const int gcol = (lane & 3) * 8;
    unsigned short* lA = Ps + w * 1024;
    unsigned short* lB = Vs + w * 1024;

    f32x4 acc[4][4];
#pragma unroll
    for (int a = 0; a < 4; ++a)
#pragma unroll
        for (int bq = 0; bq < 4; ++bq) acc[a][bq] = (f32x4){0.f, 0.f, 0.f, 0.f};

    const int njs = i0 / 32 + 4;  // covers cols < i0+128

    for (int ks = 0; ks < njs; ++ks) {
        const int j0 = ks * 32;
        __syncthreads();
        {
            const unsigned short* gp = Pm + ((size_t)b * SEQ + i0 + grow) * SEQ + j0 + gcol;
            const unsigned short* gv = Vt + ((size_t)b * DIM + d0 + grow) * SEQ + j0 + gcol;
            gld_lds16(gp, lA);
            gld_lds16(gp + (size_t)16 * SEQ, lA + 512);
            gld_lds16(gv, lB);
            gld_lds16(gv + (size_t)16 * SEQ, lB + 512);
        }
        __syncthreads();
        bf16x8 ah[4], bh[4];
#pragma unroll
        for (int mi = 0; mi < 4; ++mi)
            ah[mi] = ldsld(Ps + (wrow + mi * 16 + c) * 32 + q * 8);
#pragma unroll
        for (int ni = 0; ni < 4; ++ni)
            bh[ni] = ldsld(Vs + (wcol + ni * 16 + c) * 32 + q * 8);
#pragma unroll
        for (int mi = 0; mi < 4; ++mi)
#pragma unroll
            for (int ni = 0; ni < 4; ++ni)
                acc[mi][ni] = __builtin_amdgcn_mfma_f32_16x16x32_bf16(ah[mi], bh[ni], acc[mi][ni], 0, 0, 0);
    }
#pragma unroll
    for (int mi = 0; mi < 4; ++mi)
#pragma unroll
        for (int ni = 0; ni < 4; ++ni) {
            const int dcol = d0 + wcol + ni * 16 + c;
#pragma unroll
            for (int r = 0; r < 4; ++r) {
                const int i = i0 + wrow + mi * 16 + q * 4 + r;
                Out[((size_t)b * SEQ + i) * DIM + dcol] = acc[mi][ni][r];
            }
        }
}

extern "C" void kernel_launch(void* const* d_in, const int* in_sizes, int n_in,
                              void* d_out, int out_size, void* d_ws, size_t ws_size,
                              hipStream_t stream)
{
    (void)out_size; (void)ws_size;
    const float* X = nullptr;
    const float* Wv[3] = {nullptr, nullptr, nullptr};
    int nw = 0;
    for (int i = 0; i < n_in; ++i) {
        if (in_sizes[i] == (int)NBS)
            X = (const float*)d_in[i];
        else if (nw < 3)
            Wv[nw++] = (const float*)d_in[i];
    }

    unsigned short* ws = (unsigned short*)d_ws;
    unsigned short* Qh = ws;                 // 16 MB
    unsigned short* Kh = ws + NBS;           // 16 MB
    unsigned short* Vt = ws + 2 * NBS;       // 16 MB
    unsigned short* Xh = ws + 3 * NBS;       // consumed by qk/v gemms
    unsigned short* Xl = ws + 4 * NBS;
    unsigned short* Pp = ws + 3 * NBS;       // P aliases Xh/Xl after qkv (32 MB)
    unsigned short* Sb = ws + 5 * NBS;       // bf16 S, all batches (32 MB)
    unsigned short* Wh = ws + 7 * NBS;       // 6 MB
    unsigned short* Wl = Wh + (size_t)3 * DIM * DIM;  // 6 MB  (peak 124 MB)
    float* Out = (float*)d_out;

    split_f32<<<dim3((int)(NBS / 4 / 256)), 256, 0, stream>>>(X, Xh, Xl, (int)(NBS / 4));
    const int wn4 = DIM * DIM / 4;
    for (int z = 0; z < 3; ++z)
        split_f32<<<dim3(wn4 / 256), 256, 0, stream>>>(
            Wv[z], Wh + (size_t)z * DIM * DIM, Wl + (size_t)z * DIM * DIM, wn4);

    qk_gemm3<<<dim3(64, 8, 2), 256, 0, stream>>>(Xh, Xl, Wh, Wl, Qh, Kh);
    v_gemm1<<<dim3(64, 8), 256, 0, stream>>>(Xh, Wh + (size_t)2 * DIM * DIM, Vt);

    scores_gemm1b<<<dim3(16, 16, BATCH), 256, 0, stream>>>(Qh, Kh, Sb);
    softmax_row_b<<<dim3(SEQ, BATCH), 256, 0, stream>>>(Sb, Pp);

    pv_gemm<<<dim3(16, 8, BATCH), 256, 0, stream>>>(Pp, Vt, Out);
}

// Round 2
// 277.866 us; speedup vs baseline: 1.3540x; 1.2323x over previous
//
#include <hip/hip_runtime.h>

typedef _Float16 f16x8 __attribute__((ext_vector_type(8)));
typedef unsigned short u16x8v __attribute__((ext_vector_type(8)));
typedef unsigned short u16x4v __attribute__((ext_vector_type(4)));
typedef float f32x4 __attribute__((ext_vector_type(4)));

constexpr int SEQ = 2048;
constexpr int DIM = 1024;
constexpr int BATCH = 4;
constexpr size_t NBS = (size_t)BATCH * SEQ * DIM;  // 8388608

static __device__ __forceinline__ unsigned short f2h(float f) {
    return __builtin_bit_cast(unsigned short, (_Float16)f);  // RNE
}
static __device__ __forceinline__ float h2f(unsigned short u) {
    return (float)__builtin_bit_cast(_Float16, u);
}
static __device__ __forceinline__ f16x8 ldsld(const unsigned short* p) {
    return __builtin_bit_cast(f16x8, *(const u16x8v*)p);
}
// Async global->LDS, 16B/lane. LDS dest = wave-uniform base + lane*16B.
static __device__ __forceinline__ void gld_lds16(const unsigned short* g, unsigned short* l) {
    __builtin_amdgcn_global_load_lds(
        (const __attribute__((address_space(1))) void*)g,
        (__attribute__((address_space(3))) void*)l, 16, 0, 0);
}

// ---------------------------------------------------------------------------
// fp32 -> fp16 convert, 4 elems/thread.
// ---------------------------------------------------------------------------
__global__ __launch_bounds__(256) void cvt_f16(
    const float* __restrict__ in, unsigned short* __restrict__ out, int n4)
{
    int i = blockIdx.x * 256 + threadIdx.x;
    if (i >= n4) return;
    float4 f = ((const float4*)in)[i];
    u16x4v h;
    h.x = f2h(f.x); h.y = f2h(f.y); h.z = f2h(f.z); h.w = f2h(f.w);
    ((u16x4v*)out)[i] = h;
}

// ---------------------------------------------------------------------------
// Fused Q/K/V projection, single fp16 MFMA term (fp16 input precision 2^-11
// is below the fp16 intermediate-storage rounding that dominates the error
// budget; replaces bf16 split-3). NT, W [out,in]. 128x128 tile, 4 waves x
// 64x64 (4x4 MFMA 16x16x32_f16). z=0 -> Qf, z=1 -> Kf, z=2 -> Vt transposed.
// Staging via global_load_lds width=16, linear [128][32] LDS tiles.
// ---------------------------------------------------------------------------
__global__ __launch_bounds__(256) void qkv_gemm(
    const unsigned short* __restrict__ Xf, const unsigned short* __restrict__ Wf,
    unsigned short* __restrict__ Qf, unsigned short* __restrict__ Kf,
    unsigned short* __restrict__ Vt)
{
    __shared__ __attribute__((aligned(16))) unsigned short Ah[128 * 32];
    __shared__ __attribute__((aligned(16))) unsigned short Bh[128 * 32];
    const int m0 = blockIdx.x * 128, n0 = blockIdx.y * 128, z = blockIdx.z;
    const unsigned short* Wz = Wf + (size_t)z * DIM * DIM;
    const int tid = threadIdx.x;
    const int w = tid >> 6, lane = tid & 63, q = lane >> 4, c = lane & 15;
    const int wrow = (w >> 1) * 64, wcol = (w & 1) * 64;
    const int grow = w * 32 + (lane >> 2);   // staging row (first call)
    const int gcol = (lane & 3) * 8;         // staging col offset (shorts)
    unsigned short* lA = Ah + w * 1024;      // wave-uniform LDS bases
    unsigned short* lB = Bh + w * 1024;

    f32x4 acc[4][4];
#pragma unroll
    for (int a = 0; a < 4; ++a)
#pragma unroll
        for (int b = 0; b < 4; ++b) acc[a][b] = (f32x4){0.f, 0.f, 0.f, 0.f};

    for (int k0 = 0; k0 < DIM; k0 += 32) {
        __syncthreads();
        {
            const size_t ga = (size_t)(m0 + grow) * DIM + k0 + gcol;
            const size_t gb = (size_t)(n0 + grow) * DIM + k0 + gcol;
            gld_lds16(Xf + ga, lA);
            gld_lds16(Xf + ga + (size_t)16 * DIM, lA + 512);
            gld_lds16(Wz + gb, lB);
            gld_lds16(Wz + gb + (size_t)16 * DIM, lB + 512);
        }
        __syncthreads();
        f16x8 ah[4], bh[4];
#pragma unroll
        for (int mi = 0; mi < 4; ++mi)
            ah[mi] = ldsld(Ah + (wrow + mi * 16 + c) * 32 + q * 8);
#pragma unroll
        for (int ni = 0; ni < 4; ++ni)
            bh[ni] = ldsld(Bh + (wcol + ni * 16 + c) * 32 + q * 8);
#pragma unroll
        for (int mi = 0; mi < 4; ++mi)
#pragma unroll
            for (int ni = 0; ni < 4; ++ni)
                acc[mi][ni] = __builtin_amdgcn_mfma_f32_16x16x32_f16(ah[mi], bh[ni], acc[mi][ni], 0, 0, 0);
    }

    if (z == 2) {
        // V: store transposed Vt[b][d][s], fp16.
#pragma unroll
        for (int mi = 0; mi < 4; ++mi) {
            const int mg = m0 + wrow + mi * 16 + q * 4;
            const int bb = mg >> 11, ss = mg & (SEQ - 1);
#pragma unroll
            for (int ni = 0; ni < 4; ++ni) {
                const int col = n0 + wcol + ni * 16 + c;
                u16x4v v;
                v.x = f2h(acc[mi][ni][0]);
                v.y = f2h(acc[mi][ni][1]);
                v.z = f2h(acc[mi][ni][2]);
                v.w = f2h(acc[mi][ni][3]);
                *(u16x4v*)(Vt + ((size_t)bb * DIM + col) * SEQ + ss) = v;
            }
        }
    } else {
        unsigned short* OH = z ? Kf : Qf;
#pragma unroll
        for (int mi = 0; mi < 4; ++mi)
#pragma unroll
            for (int ni = 0; ni < 4; ++ni) {
                const int col = n0 + wcol + ni * 16 + c;
#pragma unroll
                for (int r = 0; r < 4; ++r) {
                    const int row = m0 + wrow + mi * 16 + q * 4 + r;
                    OH[(size_t)row * DIM + col] = f2h(acc[mi][ni][r]);
                }
            }
    }
}

// ---------------------------------------------------------------------------
// Scores GEMM, ALL batches: S = Qf Kf^T * SCALE, fp16 out. Faithful masking
// of scores==0 done HERE on the f32 accumulator (pre-fp16-rounding): writes
// fp16 -inf (0xFC00). Grid (16,16,BATCH); skips tiles above the diagonal.
// ---------------------------------------------------------------------------
__global__ __launch_bounds__(256) void scores_gemm1b(
    const unsigned short* __restrict__ Q, const unsigned short* __restrict__ K,
    unsigned short* __restrict__ S)
{
    if (blockIdx.y > blockIdx.x) return;
    __shared__ __attribute__((aligned(16))) unsigned short Ah[128 * 32];
    __shared__ __attribute__((aligned(16))) unsigned short Bh[128 * 32];
    const int i0 = blockIdx.x * 128, j0 = blockIdx.y * 128, b = blockIdx.z;
    const unsigned short* Qb = Q + (size_t)b * SEQ * DIM;
    const unsigned short* Kb = K + (size_t)b * SEQ * DIM;
    unsigned short* Sb = S + (size_t)b * SEQ * SEQ;
    const int tid = threadIdx.x;
    const int w = tid >> 6, lane = tid & 63, q = lane >> 4, c = lane & 15;
    const int wrow = (w >> 1) * 64, wcol = (w & 1) * 64;
    const int grow = w * 32 + (lane >> 2);
    const int gcol = (lane & 3) * 8;
    unsigned short* lA = Ah + w * 1024;
    unsigned short* lB = Bh + w * 1024;

    f32x4 acc[4][4];
#pragma unroll
    for (int a = 0; a < 4; ++a)
#pragma unroll
        for (int bq = 0; bq < 4; ++bq) acc[a][bq] = (f32x4){0.f, 0.f, 0.f, 0.f};

    for (int k0 = 0; k0 < DIM; k0 += 32) {
        __syncthreads();
        {
            const size_t ga = (size_t)(i0 + grow) * DIM + k0 + gcol;
            const size_t gb = (size_t)(j0 + grow) * DIM + k0 + gcol;
            gld_lds16(Qb + ga, lA);
            gld_lds16(Qb + ga + (size_t)16 * DIM, lA + 512);
            gld_lds16(Kb + gb, lB);
            gld_lds16(Kb + gb + (size_t)16 * DIM, lB + 512);
        }
        __syncthreads();
        f16x8 ah[4], bh[4];
#pragma unroll
        for (int mi = 0; mi < 4; ++mi)
            ah[mi] = ldsld(Ah + (wrow + mi * 16 + c) * 32 + q * 8);
#pragma unroll
        for (int ni = 0; ni < 4; ++ni)
            bh[ni] = ldsld(Bh + (wcol + ni * 16 + c) * 32 + q * 8);
#pragma unroll
        for (int mi = 0; mi < 4; ++mi)
#pragma unroll
            for (int ni = 0; ni < 4; ++ni)
                acc[mi][ni] = __builtin_amdgcn_mfma_f32_16x16x32_f16(ah[mi], bh[ni], acc[mi][ni], 0, 0, 0);
    }
#pragma unroll
    for (int mi = 0; mi < 4; ++mi)
#pragma unroll
        for (int ni = 0; ni < 4; ++ni) {
            const int col = j0 + wcol + ni * 16 + c;
#pragma unroll
            for (int r = 0; r < 4; ++r) {
                const int row = i0 + wrow + mi * 16 + q * 4 + r;
                const float sc = acc[mi][ni][r] * 0.03125f;
                Sb[(size_t)row * SEQ + col] =
                    (sc == 0.f) ? (unsigned short)0xFC00u : f2h(sc);
            }
        }
}

// ---------------------------------------------------------------------------
// Row-wise masked softmax, ALL batches: fp16 S -> fp16 P (full rows).
// j > i masked here; scores==0 already -inf from the scores epilogue.
// Grid (SEQ, BATCH). Thread t owns the contiguous chunk [8t, 8t+8).
// ---------------------------------------------------------------------------
__global__ __launch_bounds__(256) void softmax_row_b(
    const unsigned short* __restrict__ S, unsigned short* __restrict__ P)
{
    const int i = blockIdx.x, t = threadIdx.x;
    const size_t ro = ((size_t)blockIdx.y * SEQ + i) * SEQ;
    const int wid = t >> 6, lane = t & 63;
    __shared__ float redm[4], reds[4];
    const int j0 = t * 8;
    u16x8v raw = *(const u16x8v*)(S + ro + j0);
    float sv[8];
    float mx = -__builtin_inff();
#pragma unroll
    for (int u = 0; u < 8; ++u) {
        float s = (j0 + u <= i) ? h2f(raw[u]) : -__builtin_inff();
        sv[u] = s;
        mx = fmaxf(mx, s);
    }
#pragma unroll
    for (int off = 1; off < 64; off <<= 1) mx = fmaxf(mx, __shfl_xor(mx, off));
    if (lane == 0) redm[wid] = mx;
    __syncthreads();
    const float M = fmaxf(fmaxf(redm[0], redm[1]), fmaxf(redm[2], redm[3]));
    float sum = 0.f;
#pragma unroll
    for (int u = 0; u < 8; ++u) {
        float e = __expf(sv[u] - M);
        sv[u] = e;
        sum += e;
    }
#pragma unroll
    for (int off = 1; off < 64; off <<= 1) sum += __shfl_xor(sum, off);
    if (lane == 0) reds[wid] = sum;
    __syncthreads();
    const float rinv = 1.f / (reds[0] + reds[1] + reds[2] + reds[3]);
    u16x8v o;
#pragma unroll
    for (int u = 0; u < 8; ++u) o[u] = f2h(sv[u] * rinv);
    *(u16x8v*)(P + ro + j0) = o;
}

// ---------------------------------------------------------------------------
// out = P @ V via Vt (NT MFMA, fp16), fp32 store. 128x128 tile (4x4 acc);
// k-loop truncated at causal bound i0+128.
// ---------------------------------------------------------------------------
__global__ __launch_bounds__(256) void pv_gemm(
    const unsigned short* __restrict__ Pm, const unsigned short* __restrict__ Vt,
    float* __restrict__ Out)
{
    __shared__ __attribute__((aligned(16))) unsigned short Ps[128 * 32];
    __shared__ __attribute__((aligned(16))) unsigned short Vs[128 * 32];
    const int i0 = blockIdx.x * 128, d0 = blockIdx.y * 128, b = blockIdx.z;
    const int tid = threadIdx.x;
    const int w = tid >> 6, lane = tid & 63, q = lane >> 4, c = lane & 15;
    const int wrow = (w >> 1) * 64, wcol = (w & 1) * 64;
    const int grow = w * 32 + (lane >> 2);
    const int gcol = (lane & 3) * 8;
    unsigned short* lA = Ps + w * 1024;
    unsigned short* lB = Vs + w * 1024;

    f32x4 acc[4][4];
#pragma unroll
    for (int a = 0; a < 4; ++a)
#pragma unroll
        for (int bq = 0; bq < 4; ++bq) acc[a][bq] = (f32x4){0.f, 0.f, 0.f, 0.f};

    const int njs = i0 / 32 + 4;  // covers cols < i0+128

    for (int ks = 0; ks < njs; ++ks) {
        const int j0 = ks * 32;
        __syncthreads();
        {
            const unsigned short* gp = Pm + ((size_t)b * SEQ + i0 + grow) * SEQ + j0 + gcol;
            const unsigned short* gv = Vt + ((size_t)b * DIM + d0 + grow) * SEQ + j0 + gcol;
            gld_lds16(gp, lA);
            gld_lds16(gp + (size_t)16 * SEQ, lA + 512);
            gld_lds16(gv, lB);
            gld_lds16(gv + (size_t)16 * SEQ, lB + 512);
        }
        __syncthreads();
        f16x8 ah[4], bh[4];
#pragma unroll
        for (int mi = 0; mi < 4; ++mi)
            ah[mi] = ldsld(Ps + (wrow + mi * 16 + c) * 32 + q * 8);
#pragma unroll
        for (int ni = 0; ni < 4; ++ni)
            bh[ni] = ldsld(Vs + (wcol + ni * 16 + c) * 32 + q * 8);
#pragma unroll
        for (int mi = 0; mi < 4; ++mi)
#pragma unroll
            for (int ni = 0; ni < 4; ++ni)
                acc[mi][ni] = __builtin_amdgcn_mfma_f32_16x16x32_f16(ah[mi], bh[ni], acc[mi][ni], 0, 0, 0);
    }
#pragma unroll
    for (int mi = 0; mi < 4; ++mi)
#pragma unroll
        for (int ni = 0; ni < 4; ++ni) {
            const int dcol = d0 + wcol + ni * 16 + c;
#pragma unroll
            for (int r = 0; r < 4; ++r) {
                const int i = i0 + wrow + mi * 16 + q * 4 + r;
                Out[((size_t)b * SEQ + i) * DIM + dcol] = acc[mi][ni][r];
            }
        }
}

extern "C" void kernel_launch(void* const* d_in, const int* in_sizes, int n_in,
                              void* d_out, int out_size, void* d_ws, size_t ws_size,
                              hipStream_t stream)
{
    (void)out_size; (void)ws_size;
    const float* X = nullptr;
    const float* Wv[3] = {nullptr, nullptr, nullptr};
    int nw = 0;
    for (int i = 0; i < n_in; ++i) {
        if (in_sizes[i] == (int)NBS)
            X = (const float*)d_in[i];
        else if (nw < 3)
            Wv[nw++] = (const float*)d_in[i];
    }

    unsigned short* ws = (unsigned short*)d_ws;
    unsigned short* Qf = ws;                 // 16 MB
    unsigned short* Kf = ws + NBS;           // 16 MB
    unsigned short* Vt = ws + 2 * NBS;       // 16 MB
    unsigned short* Xf = ws + 3 * NBS;       // consumed by qkv gemm
    unsigned short* Pp = ws + 3 * NBS;       // P aliases Xf after qkv (32 MB)
    unsigned short* Sb = ws + 5 * NBS;       // fp16 S, all batches (32 MB)
    unsigned short* Wf = ws + 7 * NBS;       // 6 MB
    float* Out = (float*)d_out;

    cvt_f16<<<dim3((int)(NBS / 4 / 256)), 256, 0, stream>>>(X, Xf, (int)(NBS / 4));
    const int wn4 = DIM * DIM / 4;
    for (int z = 0; z < 3; ++z)
        cvt_f16<<<dim3(wn4 / 256), 256, 0, stream>>>(
            Wv[z], Wf + (size_t)z * DIM * DIM, wn4);

    qkv_gemm<<<dim3(64, 8, 3), 256, 0, stream>>>(Xf, Wf, Qf, Kf, Vt);

    scores_gemm1b<<<dim3(16, 16, BATCH), 256, 0, stream>>>(Qf, Kf, Sb);
    softmax_row_b<<<dim3(SEQ, BATCH), 256, 0, stream>>>(Sb, Pp);

    pv_gemm<<<dim3(16, 8, BATCH), 256, 0, stream>>>(Pp, Vt, Out);
}

// Round 3
// 243.075 us; speedup vs baseline: 1.5478x; 1.1431x over previous
//
#include <hip/hip_runtime.h>

typedef _Float16 f16x8 __attribute__((ext_vector_type(8)));
typedef unsigned short u16x8v __attribute__((ext_vector_type(8)));
typedef unsigned short u16x4v __attribute__((ext_vector_type(4)));
typedef float f32x4 __attribute__((ext_vector_type(4)));

constexpr int SEQ = 2048;
constexpr int DIM = 1024;
constexpr int BATCH = 4;
constexpr size_t NBS = (size_t)BATCH * SEQ * DIM;  // 8388608

static __device__ __forceinline__ unsigned short f2h(float f) {
    return __builtin_bit_cast(unsigned short, (_Float16)f);  // RNE
}
static __device__ __forceinline__ float h2f(unsigned short u) {
    return (float)__builtin_bit_cast(_Float16, u);
}
static __device__ __forceinline__ f16x8 ldsld(const unsigned short* p) {
    return __builtin_bit_cast(f16x8, *(const u16x8v*)p);
}
// Async global->LDS, 16B/lane. LDS dest = wave-uniform base + lane*16B.
static __device__ __forceinline__ void gld_lds16(const unsigned short* g, unsigned short* l) {
    __builtin_amdgcn_global_load_lds(
        (const __attribute__((address_space(1))) void*)g,
        (__attribute__((address_space(3))) void*)l, 16, 0, 0);
}

// ---------------------------------------------------------------------------
// fp32 -> fp16 convert, X + all 3 W in ONE launch (saves 3 launch overheads).
// Blocks [0,8192): X (2097152 float4s). Blocks [8192, 8192+3072): W0..W2.
// ---------------------------------------------------------------------------
__global__ __launch_bounds__(256) void cvt_all(
    const float* __restrict__ X,
    const float* __restrict__ W0, const float* __restrict__ W1,
    const float* __restrict__ W2,
    unsigned short* __restrict__ Xf, unsigned short* __restrict__ Wf)
{
    const int b = blockIdx.x;
    const float* src;
    unsigned short* dst;
    int i;
    if (b < 8192) {
        src = X; dst = Xf;
        i = b * 256 + threadIdx.x;
    } else {
        const int wb = b - 8192;
        const int z = wb >> 10;              // 1024 blocks per weight
        src = (z == 0) ? W0 : (z == 1) ? W1 : W2;
        dst = Wf + (size_t)z * DIM * DIM;
        i = (wb & 1023) * 256 + threadIdx.x;
    }
    float4 f = ((const float4*)src)[i];
    u16x4v h;
    h.x = f2h(f.x); h.y = f2h(f.y); h.z = f2h(f.z); h.w = f2h(f.w);
    ((u16x4v*)dst)[i] = h;
}

// ---------------------------------------------------------------------------
// Swizzled staging (rule 21: linear gld_lds dest + inverse-swizzled global
// source + swizzled read). Tile = [128 rows][64 shorts] = 16KB, row = 8 units
// of 16B; LDS unit u holds global (row=u>>3, colunit=(u&7)^(row&7)).
// Read of (row, cu) uses unit row*8 + (cu^(row&7)) -> bank-conflict-free.
// BK=64: 32 MFMA per barrier pair (2x the amortization of BK=32).
// ---------------------------------------------------------------------------

// ---------------------------------------------------------------------------
// Fused Q/K/V projection, fp16 MFMA. z=0 -> Qf, z=1 -> Kf, z=2 -> Vt (transposed).
// 128x128 tile, 4 waves x 64x64 (4x4 MFMA 16x16x32_f16), BK=64 swizzled.
// ---------------------------------------------------------------------------
__global__ __launch_bounds__(256) void qkv_gemm(
    const unsigned short* __restrict__ Xf, const unsigned short* __restrict__ Wf,
    unsigned short* __restrict__ Qf, unsigned short* __restrict__ Kf,
    unsigned short* __restrict__ Vt)
{
    __shared__ __attribute__((aligned(16))) unsigned short Ah[128 * 64];
    __shared__ __attribute__((aligned(16))) unsigned short Bh[128 * 64];
    const int m0 = blockIdx.x * 128, n0 = blockIdx.y * 128, z = blockIdx.z;
    const unsigned short* Wz = Wf + (size_t)z * DIM * DIM;
    const int tid = threadIdx.x;
    const int w = tid >> 6, lane = tid & 63, q = lane >> 4, c = lane & 15;
    const int wrow = (w >> 1) * 64, wcol = (w & 1) * 64;
    const int g8 = lane >> 3;                 // row-in-group 0..7
    const int cu = (lane & 7) ^ g8;           // inverse-swizzled col unit
    const int srow = w * 8 + g8;              // staging row (call j adds j*32)
    const int scol = cu * 8;                  // shorts
    unsigned short* lA = Ah + w * 512;        // wave-uniform LDS bases
    unsigned short* lB = Bh + w * 512;
    const int c7 = c & 7;

    f32x4 acc[4][4];
#pragma unroll
    for (int a = 0; a < 4; ++a)
#pragma unroll
        for (int b = 0; b < 4; ++b) acc[a][b] = (f32x4){0.f, 0.f, 0.f, 0.f};

    for (int k0 = 0; k0 < DIM; k0 += 64) {
        __syncthreads();
        {
            const size_t ga = (size_t)(m0 + srow) * DIM + k0 + scol;
            const size_t gb = (size_t)(n0 + srow) * DIM + k0 + scol;
#pragma unroll
            for (int j = 0; j < 4; ++j) {
                gld_lds16(Xf + ga + (size_t)(j * 32) * DIM, lA + j * 2048);
                gld_lds16(Wz + gb + (size_t)(j * 32) * DIM, lB + j * 2048);
            }
        }
        __syncthreads();
#pragma unroll
        for (int kk = 0; kk < 2; ++kk) {
            f16x8 ah[4], bh[4];
#pragma unroll
            for (int mi = 0; mi < 4; ++mi)
                ah[mi] = ldsld(Ah + (wrow + mi * 16 + c) * 64 + (((kk << 2) + q) ^ c7) * 8);
#pragma unroll
            for (int ni = 0; ni < 4; ++ni)
                bh[ni] = ldsld(Bh + (wcol + ni * 16 + c) * 64 + (((kk << 2) + q) ^ c7) * 8);
#pragma unroll
            for (int mi = 0; mi < 4; ++mi)
#pragma unroll
                for (int ni = 0; ni < 4; ++ni)
                    acc[mi][ni] = __builtin_amdgcn_mfma_f32_16x16x32_f16(ah[mi], bh[ni], acc[mi][ni], 0, 0, 0);
        }
    }

    if (z == 2) {
        // V: store transposed Vt[b][d][s], fp16.
#pragma unroll
        for (int mi = 0; mi < 4; ++mi) {
            const int mg = m0 + wrow + mi * 16 + q * 4;
            const int bb = mg >> 11, ss = mg & (SEQ - 1);
#pragma unroll
            for (int ni = 0; ni < 4; ++ni) {
                const int col = n0 + wcol + ni * 16 + c;
                u16x4v v;
                v.x = f2h(acc[mi][ni][0]);
                v.y = f2h(acc[mi][ni][1]);
                v.z = f2h(acc[mi][ni][2]);
                v.w = f2h(acc[mi][ni][3]);
                *(u16x4v*)(Vt + ((size_t)bb * DIM + col) * SEQ + ss) = v;
            }
        }
    } else {
        unsigned short* OH = z ? Kf : Qf;
#pragma unroll
        for (int mi = 0; mi < 4; ++mi)
#pragma unroll
            for (int ni = 0; ni < 4; ++ni) {
                const int col = n0 + wcol + ni * 16 + c;
#pragma unroll
                for (int r = 0; r < 4; ++r) {
                    const int row = m0 + wrow + mi * 16 + q * 4 + r;
                    OH[(size_t)row * DIM + col] = f2h(acc[mi][ni][r]);
                }
            }
    }
}

// ---------------------------------------------------------------------------
// Scores GEMM, ALL batches: S = Qf Kf^T * SCALE, fp16 out. Faithful masking
// of scores==0 on the f32 accumulator (pre-fp16-rounding): writes 0xFC00.
// Grid (16,16,BATCH); skips tiles above the diagonal. BK=64 swizzled.
// ---------------------------------------------------------------------------
__global__ __launch_bounds__(256) void scores_gemm1b(
    const unsigned short* __restrict__ Q, const unsigned short* __restrict__ K,
    unsigned short* __restrict__ S)
{
    if (blockIdx.y > blockIdx.x) return;
    __shared__ __attribute__((aligned(16))) unsigned short Ah[128 * 64];
    __shared__ __attribute__((aligned(16))) unsigned short Bh[128 * 64];
    const int i0 = blockIdx.x * 128, j0 = blockIdx.y * 128, b = blockIdx.z;
    const unsigned short* Qb = Q + (size_t)b * SEQ * DIM;
    const unsigned short* Kb = K + (size_t)b * SEQ * DIM;
    unsigned short* Sb = S + (size_t)b * SEQ * SEQ;
    const int tid = threadIdx.x;
    const int w = tid >> 6, lane = tid & 63, q = lane >> 4, c = lane & 15;
    const int wrow = (w >> 1) * 64, wcol = (w & 1) * 64;
    const int g8 = lane >> 3;
    const int cu = (lane & 7) ^ g8;
    const int srow = w * 8 + g8;
    const int scol = cu * 8;
    unsigned short* lA = Ah + w * 512;
    unsigned short* lB = Bh + w * 512;
    const int c7 = c & 7;

    f32x4 acc[4][4];
#pragma unroll
    for (int a = 0; a < 4; ++a)
#pragma unroll
        for (int bq = 0; bq < 4; ++bq) acc[a][bq] = (f32x4){0.f, 0.f, 0.f, 0.f};

    for (int k0 = 0; k0 < DIM; k0 += 64) {
        __syncthreads();
        {
            const size_t ga = (size_t)(i0 + srow) * DIM + k0 + scol;
            const size_t gb = (size_t)(j0 + srow) * DIM + k0 + scol;
#pragma unroll
            for (int j = 0; j < 4; ++j) {
                gld_lds16(Qb + ga + (size_t)(j * 32) * DIM, lA + j * 2048);
                gld_lds16(Kb + gb + (size_t)(j * 32) * DIM, lB + j * 2048);
            }
        }
        __syncthreads();
#pragma unroll
        for (int kk = 0; kk < 2; ++kk) {
            f16x8 ah[4], bh[4];
#pragma unroll
            for (int mi = 0; mi < 4; ++mi)
                ah[mi] = ldsld(Ah + (wrow + mi * 16 + c) * 64 + (((kk << 2) + q) ^ c7) * 8);
#pragma unroll
            for (int ni = 0; ni < 4; ++ni)
                bh[ni] = ldsld(Bh + (wcol + ni * 16 + c) * 64 + (((kk << 2) + q) ^ c7) * 8);
#pragma unroll
            for (int mi = 0; mi < 4; ++mi)
#pragma unroll
                for (int ni = 0; ni < 4; ++ni)
                    acc[mi][ni] = __builtin_amdgcn_mfma_f32_16x16x32_f16(ah[mi], bh[ni], acc[mi][ni], 0, 0, 0);
        }
    }
#pragma unroll
    for (int mi = 0; mi < 4; ++mi)
#pragma unroll
        for (int ni = 0; ni < 4; ++ni) {
            const int col = j0 + wcol + ni * 16 + c;
#pragma unroll
            for (int r = 0; r < 4; ++r) {
                const int row = i0 + wrow + mi * 16 + q * 4 + r;
                const float sc = acc[mi][ni][r] * 0.03125f;
                Sb[(size_t)row * SEQ + col] =
                    (sc == 0.f) ? (unsigned short)0xFC00u : f2h(sc);
            }
        }
}

// ---------------------------------------------------------------------------
// Row-wise masked softmax: fp16 S -> fp16 P. j > i masked; scores==0 already
// -inf. Causal traffic: skip loads for chunks beyond i, skip writes beyond
// rti = rowtile end (pv never reads past it). Grid (SEQ, BATCH).
// ---------------------------------------------------------------------------
__global__ __launch_bounds__(256) void softmax_row_b(
    const unsigned short* __restrict__ S, unsigned short* __restrict__ P)
{
    const int i = blockIdx.x, t = threadIdx.x;
    const size_t ro = ((size_t)blockIdx.y * SEQ + i) * SEQ;
    const int wid = t >> 6, lane = t & 63;
    __shared__ float redm[4], reds[4];
    const int j0 = t * 8;
    const int rti = (i & ~127) + 128;        // pv reads cols < rti only
    float sv[8];
    float mx = -__builtin_inff();
    if (j0 <= i) {
        u16x8v raw = *(const u16x8v*)(S + ro + j0);
#pragma unroll
        for (int u = 0; u < 8; ++u) {
            float s = (j0 + u <= i) ? h2f(raw[u]) : -__builtin_inff();
            sv[u] = s;
            mx = fmaxf(mx, s);
        }
    } else {
#pragma unroll
        for (int u = 0; u < 8; ++u) sv[u] = -__builtin_inff();
    }
#pragma unroll
    for (int off = 1; off < 64; off <<= 1) mx = fmaxf(mx, __shfl_xor(mx, off));
    if (lane == 0) redm[wid] = mx;
    __syncthreads();
    const float M = fmaxf(fmaxf(redm[0], redm[1]), fmaxf(redm[2], redm[3]));
    float sum = 0.f;
#pragma unroll
    for (int u = 0; u < 8; ++u) {
        float e = __expf(sv[u] - M);
        sv[u] = e;
        sum += e;
    }
#pragma unroll
    for (int off = 1; off < 64; off <<= 1) sum += __shfl_xor(sum, off);
    if (lane == 0) reds[wid] = sum;
    __syncthreads();
    const float rinv = 1.f / (reds[0] + reds[1] + reds[2] + reds[3]);
    if (j0 < rti) {
        u16x8v o;
#pragma unroll
        for (int u = 0; u < 8; ++u) o[u] = f2h(sv[u] * rinv);
        *(u16x8v*)(P + ro + j0) = o;
    }
}

// ---------------------------------------------------------------------------
// out = P @ V via Vt (NT MFMA, fp16), fp32 store. 128x128 tile, BK=64
// swizzled; k-loop truncated at causal bound i0+128.
// ---------------------------------------------------------------------------
__global__ __launch_bounds__(256) void pv_gemm(
    const unsigned short* __restrict__ Pm, const unsigned short* __restrict__ Vt,
    float* __restrict__ Out)
{
    __shared__ __attribute__((aligned(16))) unsigned short Ps[128 * 64];
    __shared__ __attribute__((aligned(16))) unsigned short Vs[128 * 64];
    const int i0 = blockIdx.x * 128, d0 = blockIdx.y * 128, b = blockIdx.z;
    const int tid = threadIdx.x;
    const int w = tid >> 6, lane = tid & 63, q = lane >> 4, c = lane & 15;
    const int wrow = (w >> 1) * 64, wcol = (w & 1) * 64;
    const int g8 = lane >> 3;
    const int cu = (lane & 7) ^ g8;
    const int srow = w * 8 + g8;
    const int scol = cu * 8;
    unsigned short* lA = Ps + w * 512;
    unsigned short* lB = Vs + w * 512;
    const int c7 = c & 7;

    f32x4 acc[4][4];
#pragma unroll
    for (int a = 0; a < 4; ++a)
#pragma unroll
        for (int bq = 0; bq < 4; ++bq) acc[a][bq] = (f32x4){0.f, 0.f, 0.f, 0.f};

    const int njs = i0 / 64 + 2;  // covers cols < i0+128

    for (int ks = 0; ks < njs; ++ks) {
        const int j0 = ks * 64;
        __syncthreads();
        {
            const size_t gpa = ((size_t)b * SEQ + i0 + srow) * SEQ + j0 + scol;
            const size_t gva = ((size_t)b * DIM + d0 + srow) * SEQ + j0 + scol;
#pragma unroll
            for (int j = 0; j < 4; ++j) {
                gld_lds16(Pm + gpa + (size_t)(j * 32) * SEQ, lA + j * 2048);
                gld_lds16(Vt + gva + (size_t)(j * 32) * SEQ, lB + j * 2048);
            }
        }
        __syncthreads();
#pragma unroll
        for (int kk = 0; kk < 2; ++kk) {
            f16x8 ah[4], bh[4];
#pragma unroll
            for (int mi = 0; mi < 4; ++mi)
                ah[mi] = ldsld(Ps + (wrow + mi * 16 + c) * 64 + (((kk << 2) + q) ^ c7) * 8);
#pragma unroll
            for (int ni = 0; ni < 4; ++ni)
                bh[ni] = ldsld(Vs + (wcol + ni * 16 + c) * 64 + (((kk << 2) + q) ^ c7) * 8);
#pragma unroll
            for (int mi = 0; mi < 4; ++mi)
#pragma unroll
                for (int ni = 0; ni < 4; ++ni)
                    acc[mi][ni] = __builtin_amdgcn_mfma_f32_16x16x32_f16(ah[mi], bh[ni], acc[mi][ni], 0, 0, 0);
        }
    }
#pragma unroll
    for (int mi = 0; mi < 4; ++mi)
#pragma unroll
        for (int ni = 0; ni < 4; ++ni) {
            const int dcol = d0 + wcol + ni * 16 + c;
#pragma unroll
            for (int r = 0; r < 4; ++r) {
                const int i = i0 + wrow + mi * 16 + q * 4 + r;
                Out[((size_t)b * SEQ + i) * DIM + dcol] = acc[mi][ni][r];
            }
        }
}

extern "C" void kernel_launch(void* const* d_in, const int* in_sizes, int n_in,
                              void* d_out, int out_size, void* d_ws, size_t ws_size,
                              hipStream_t stream)
{
    (void)out_size; (void)ws_size;
    const float* X = nullptr;
    const float* Wv[3] = {nullptr, nullptr, nullptr};
    int nw = 0;
    for (int i = 0; i < n_in; ++i) {
        if (in_sizes[i] == (int)NBS)
            X = (const float*)d_in[i];
        else if (nw < 3)
            Wv[nw++] = (const float*)d_in[i];
    }

    unsigned short* ws = (unsigned short*)d_ws;
    unsigned short* Qf = ws;                 // 16 MB
    unsigned short* Kf = ws + NBS;           // 16 MB
    unsigned short* Vt = ws + 2 * NBS;       // 16 MB
    unsigned short* Xf = ws + 3 * NBS;       // consumed by qkv gemm
    unsigned short* Pp = ws + 3 * NBS;       // P aliases Xf after qkv (32 MB)
    unsigned short* Sb = ws + 5 * NBS;       // fp16 S, all batches (32 MB)
    unsigned short* Wf = ws + 7 * NBS;       // 6 MB
    float* Out = (float*)d_out;

    cvt_all<<<dim3(8192 + 3072), 256, 0, stream>>>(X, Wv[0], Wv[1], Wv[2], Xf, Wf);

    qkv_gemm<<<dim3(64, 8, 3), 256, 0, stream>>>(Xf, Wf, Qf, Kf, Vt);

    scores_gemm1b<<<dim3(16, 16, BATCH), 256, 0, stream>>>(Qf, Kf, Sb);
    softmax_row_b<<<dim3(SEQ, BATCH), 256, 0, stream>>>(Sb, Pp);

    pv_gemm<<<dim3(16, 8, BATCH), 256, 0, stream>>>(Pp, Vt, Out);
}